// Round 1
// baseline (1257.809 us; speedup 1.0000x reference)
//
#include <hip/hip_runtime.h>
#include <hip/hip_bf16.h>
#include <stdint.h>

#define D 128
#define NGRAPH 256
#define BN_EPS 1e-5f
#define TAB_ROWS 105          // 49 (a0,a1) + 49 (a2,a3) + 7 (a4)
#define TAB_SZ (TAB_ROWS * D) // 13440 floats
#define AGG_BLOCKS 512
#define AGG_THREADS 1024

// ---------------- atom embedding: h0[n][c] = sum_f atom_emb[f][x[n,f]][c] ----
__global__ void embed_kernel(const int* __restrict__ x,
                             const float* __restrict__ atom_emb,
                             float* __restrict__ h0, int n) {
  int t = blockIdx.x * blockDim.x + threadIdx.x;
  int node = t >> 5;           // 32 threads/node, 4 channels each
  int cq = t & 31;
  if (node >= n) return;
  float4 acc = {0.f, 0.f, 0.f, 0.f};
#pragma unroll
  for (int f = 0; f < 9; f++) {
    int idx = x[node * 9 + f];
    const float4* row = (const float4*)(atom_emb + ((size_t)f * 120 + idx) * D);
    float4 v = row[cq];
    acc.x += v.x; acc.y += v.y; acc.z += v.z; acc.w += v.w;
  }
  ((float4*)(h0 + (size_t)node * D))[cq] = acc;
}

// ---------------- histogram (used for edge-dst degrees and graph counts) ----
__global__ void hist_kernel(const int* __restrict__ keys, int* __restrict__ cnt, int n) {
  int i = blockIdx.x * blockDim.x + threadIdx.x;
  if (i < n) atomicAdd(&cnt[keys[i]], 1);
}

// ---------------- single-block exclusive scan (n up to ~100k) ---------------
__global__ void scan_kernel(const int* __restrict__ cnt, int* __restrict__ off,
                            int* __restrict__ cursor, int n) {
  __shared__ int sdata[1024];
  __shared__ int sbase;
  int tid = threadIdx.x;
  if (tid == 0) sbase = 0;
  __syncthreads();
  for (int start = 0; start < n; start += 1024) {
    int i = start + tid;
    int v = (i < n) ? cnt[i] : 0;
    sdata[tid] = v;
    __syncthreads();
    for (int o = 1; o < 1024; o <<= 1) {
      int t = (tid >= o) ? sdata[tid - o] : 0;
      __syncthreads();
      sdata[tid] += t;
      __syncthreads();
    }
    int excl = sbase + sdata[tid] - v;
    if (i < n) {
      off[i] = excl;
      if (cursor) cursor[i] = excl;
    }
    __syncthreads();
    if (tid == 0) sbase += sdata[1023];
    __syncthreads();
  }
  if (tid == 0) off[n] = sbase;
}

// ---------------- CSR scatter: sorted-by-dst edge records {src, packed-attr} -
__global__ void scatter_kernel(const int* __restrict__ src, const int* __restrict__ dst,
                               const int* __restrict__ attr, int* __restrict__ cursor,
                               uint2* __restrict__ edges, int ne) {
  int e = blockIdx.x * blockDim.x + threadIdx.x;
  if (e >= ne) return;
  int d = dst[e];
  int pos = atomicAdd(&cursor[d], 1);
  int a0 = attr[e * 5 + 0], a1 = attr[e * 5 + 1], a2 = attr[e * 5 + 2];
  int a3 = attr[e * 5 + 3], a4 = attr[e * 5 + 4];
  uint32_t packed = (uint32_t)(a0 * 7 + a1) | ((uint32_t)(a2 * 7 + a3) << 8) |
                    ((uint32_t)a4 << 16);
  uint2 r; r.x = (uint32_t)src[e]; r.y = packed;
  edges[pos] = r;
}

// ------- bond pair tables pre-multiplied by W^T:  tabT[r] = pairrow(r) @ W^T -
__global__ void tabT_kernel(const float* __restrict__ bond,  // [5][7][D] slice
                            const float* __restrict__ W,     // [D][D] (z=a@W^T)
                            float* __restrict__ tabT) {
  __shared__ float row[D];
  int r = blockIdx.x, c = threadIdx.x;
  float v;
  if (r < 49)
    v = bond[(0 * 7 + r / 7) * D + c] + bond[(1 * 7 + r % 7) * D + c];
  else if (r < 98) {
    int rr = r - 49;
    v = bond[(2 * 7 + rr / 7) * D + c] + bond[(3 * 7 + rr % 7) * D + c];
  } else
    v = bond[(4 * 7 + (r - 98)) * D + c];
  row[c] = v;
  __syncthreads();
  float s = 0.f;
  for (int k = 0; k < D; k++) s += row[k] * W[(size_t)c * D + k];
  tabT[(size_t)r * D + c] = s;
}

// ---------------- GEMM: out = act(in) @ W^T  (act = BN+ReLU of prev layer) --
__global__ __launch_bounds__(256) void gemm_kernel(const float* __restrict__ in,
                                                   const float* __restrict__ W,
                                                   const float* __restrict__ bnp, // scale[D],shift[D] or null
                                                   float* __restrict__ out, int M) {
  __shared__ float aT[32 * 68];   // [k][m], padded
  __shared__ float wT[32 * 132];  // [k][c], padded
  int tid = threadIdx.x;
  int m0 = blockIdx.x * 64;
  int rg = tid >> 4, cg = tid & 15;
  float acc[4][8];
#pragma unroll
  for (int r = 0; r < 4; r++)
#pragma unroll
    for (int c = 0; c < 8; c++) acc[r][c] = 0.f;

  for (int kc = 0; kc < D; kc += 32) {
    __syncthreads();
    // stage A (64 rows x 32 k), transposed, with fused BN+ReLU
#pragma unroll
    for (int j = 0; j < 2; j++) {
      int idx = tid + 256 * j;
      int row = idx >> 3, kq = idx & 7;
      int grow = m0 + row;
      float4 v = {0.f, 0.f, 0.f, 0.f};
      if (grow < M) {
        v = *(const float4*)(in + (size_t)grow * D + kc + kq * 4);
        if (bnp) {
          float4 sc = *(const float4*)(bnp + kc + kq * 4);
          float4 sh = *(const float4*)(bnp + D + kc + kq * 4);
          v.x = fmaxf(v.x * sc.x + sh.x, 0.f);
          v.y = fmaxf(v.y * sc.y + sh.y, 0.f);
          v.z = fmaxf(v.z * sc.z + sh.z, 0.f);
          v.w = fmaxf(v.w * sc.w + sh.w, 0.f);
        }
      }
      aT[(kq * 4 + 0) * 68 + row] = v.x;
      aT[(kq * 4 + 1) * 68 + row] = v.y;
      aT[(kq * 4 + 2) * 68 + row] = v.z;
      aT[(kq * 4 + 3) * 68 + row] = v.w;
    }
    // stage W (128 c x 32 k), transposed
#pragma unroll
    for (int j = 0; j < 4; j++) {
      int idx = tid + 256 * j;
      int c = idx >> 3, kq = idx & 7;
      float4 v = *(const float4*)(W + (size_t)c * D + kc + kq * 4);
      wT[(kq * 4 + 0) * 132 + c] = v.x;
      wT[(kq * 4 + 1) * 132 + c] = v.y;
      wT[(kq * 4 + 2) * 132 + c] = v.z;
      wT[(kq * 4 + 3) * 132 + c] = v.w;
    }
    __syncthreads();
#pragma unroll
    for (int k = 0; k < 32; k++) {
      float4 a4 = *(const float4*)&aT[k * 68 + rg * 4];
      float4 w0 = *(const float4*)&wT[k * 132 + cg * 8];
      float4 w1 = *(const float4*)&wT[k * 132 + cg * 8 + 4];
      float a[4] = {a4.x, a4.y, a4.z, a4.w};
      float w[8] = {w0.x, w0.y, w0.z, w0.w, w1.x, w1.y, w1.z, w1.w};
#pragma unroll
      for (int r = 0; r < 4; r++)
#pragma unroll
        for (int c = 0; c < 8; c++) acc[r][c] += a[r] * w[c];
    }
  }
#pragma unroll
  for (int r = 0; r < 4; r++) {
    int row = m0 + rg * 4 + r;
    if (row < M) {
      float4 o0 = {acc[r][0], acc[r][1], acc[r][2], acc[r][3]};
      float4 o1 = {acc[r][4], acc[r][5], acc[r][6], acc[r][7]};
      *(float4*)(out + (size_t)row * D + cg * 8) = o0;
      *(float4*)(out + (size_t)row * D + cg * 8 + 4) = o1;
    }
  }
}

// --------- aggregation: z[i] = ht[i] + lin_b + zbT + sum_in (ht[src]+ebT) ----
// also produces per-block per-channel sum / sumsq partials for BN
__global__ __launch_bounds__(AGG_THREADS) void agg_kernel(
    const float* __restrict__ ht, const float* __restrict__ tabT,
    const float* __restrict__ linb, const uint2* __restrict__ edges,
    const int* __restrict__ rowoff, float* __restrict__ z,
    float* __restrict__ partials, int n) {
  __shared__ float tabs[TAB_SZ];
  __shared__ float psum[2 * D];
  int tid = threadIdx.x;
  for (int i = tid; i < TAB_SZ / 4; i += AGG_THREADS)
    ((float4*)tabs)[i] = ((const float4*)tabT)[i];
  if (tid < 2 * D) psum[tid] = 0.f;
  __syncthreads();

  int lane = tid & 63, half = lane >> 5, cq = lane & 31;
  int wid = (blockIdx.x * AGG_THREADS + tid) >> 6;
  int nw = (gridDim.x * AGG_THREADS) >> 6;
  float4 linb4 = ((const float4*)linb)[cq];
  float4 zb4;
  {
    float4 a = ((const float4*)(tabs + 0 * D))[cq];
    float4 b = ((const float4*)(tabs + 49 * D))[cq];
    float4 c = ((const float4*)(tabs + 98 * D))[cq];
    zb4.x = a.x + b.x + c.x; zb4.y = a.y + b.y + c.y;
    zb4.z = a.z + b.z + c.z; zb4.w = a.w + b.w + c.w;
  }
  float4 ssum = {0.f, 0.f, 0.f, 0.f}, ssq = {0.f, 0.f, 0.f, 0.f};

  for (int node = wid; node < n; node += nw) {
    float4 acc = {0.f, 0.f, 0.f, 0.f};
    if (half == 0) {  // self-loop + bias init on half 0
      float4 hv = ((const float4*)(ht + (size_t)node * D))[cq];
      acc.x = hv.x + linb4.x + zb4.x;
      acc.y = hv.y + linb4.y + zb4.y;
      acc.z = hv.z + linb4.z + zb4.z;
      acc.w = hv.w + linb4.w + zb4.w;
    }
    int s = rowoff[node], e = rowoff[node + 1];
    for (int j = s + half; j < e; j += 2) {
      uint2 rec = edges[j];
      float4 hv = ((const float4*)(ht + (size_t)rec.x * D))[cq];
      uint32_t p = rec.y;
      float4 b0 = *(const float4*)(tabs + (p & 255u) * D + cq * 4);
      float4 b1 = *(const float4*)(tabs + (49u + ((p >> 8) & 255u)) * D + cq * 4);
      float4 b2 = *(const float4*)(tabs + (98u + (p >> 16)) * D + cq * 4);
      acc.x += hv.x + b0.x + b1.x + b2.x;
      acc.y += hv.y + b0.y + b1.y + b2.y;
      acc.z += hv.z + b0.z + b1.z + b2.z;
      acc.w += hv.w + b0.w + b1.w + b2.w;
    }
    acc.x += __shfl_xor(acc.x, 32, 64);
    acc.y += __shfl_xor(acc.y, 32, 64);
    acc.z += __shfl_xor(acc.z, 32, 64);
    acc.w += __shfl_xor(acc.w, 32, 64);
    if (half == 0) {
      ((float4*)(z + (size_t)node * D))[cq] = acc;
      ssum.x += acc.x; ssum.y += acc.y; ssum.z += acc.z; ssum.w += acc.w;
      ssq.x += acc.x * acc.x; ssq.y += acc.y * acc.y;
      ssq.z += acc.z * acc.z; ssq.w += acc.w * acc.w;
    }
  }
  if (half == 0) {
    int c0 = cq * 4;
    atomicAdd(&psum[c0 + 0], ssum.x);
    atomicAdd(&psum[c0 + 1], ssum.y);
    atomicAdd(&psum[c0 + 2], ssum.z);
    atomicAdd(&psum[c0 + 3], ssum.w);
    atomicAdd(&psum[D + c0 + 0], ssq.x);
    atomicAdd(&psum[D + c0 + 1], ssq.y);
    atomicAdd(&psum[D + c0 + 2], ssq.z);
    atomicAdd(&psum[D + c0 + 3], ssq.w);
  }
  __syncthreads();
  if (tid < 2 * D) partials[(size_t)blockIdx.x * 2 * D + tid] = psum[tid];
}

// ---------------- BN finalize: mu/var -> per-channel scale/shift ------------
__global__ void bn_finalize(const float* __restrict__ partials,
                            const float* __restrict__ gamma,
                            const float* __restrict__ beta,
                            float* __restrict__ bnp, int nblocks, int N) {
  int c = threadIdx.x;  // 128
  float s = 0.f, q = 0.f;
  for (int b = 0; b < nblocks; b++) {
    s += partials[(size_t)b * 2 * D + c];
    q += partials[(size_t)b * 2 * D + D + c];
  }
  float invN = 1.f / (float)N;
  float mu = s * invN;
  float var = q * invN - mu * mu;
  float rstd = rsqrtf(var + BN_EPS);
  float sc = rstd * gamma[c];
  bnp[c] = sc;
  bnp[D + c] = beta[c] - mu * sc;
}

// ---------------- mean pool over sorted batch segments ----------------------
__global__ void pool_kernel(const float* __restrict__ z, const float* __restrict__ bnp3,
                            const int* __restrict__ goff, const int* __restrict__ gcnt,
                            float* __restrict__ pool) {
  int g = blockIdx.x, c = threadIdx.x;  // 128 threads
  float sc = bnp3[c], sh = bnp3[D + c];
  int s = goff[g], cnt = gcnt[g];
  float acc = 0.f;
  for (int i = 0; i < cnt; i++) {
    float zv = z[(size_t)(s + i) * D + c];
    acc += fmaxf(zv * sc + sh, 0.f);
  }
  pool[(size_t)g * D + c] = acc / fmaxf((float)cnt, 1.f);
}

// ---------------- MLP head: out = relu(g@W1^T+b1)@W2^T + b2 -----------------
__global__ void mlp_kernel(const float* __restrict__ pool, const float* __restrict__ w1,
                           const float* __restrict__ b1, const float* __restrict__ w2,
                           const float* __restrict__ b2, float* __restrict__ out) {
  int g = blockIdx.x, j = threadIdx.x;  // 64 threads = 1 wave
  float s = b1[j];
  for (int k = 0; k < D; k++) s += pool[(size_t)g * D + k] * w1[(size_t)j * D + k];
  s = fmaxf(s, 0.f) * w2[j];
#pragma unroll
  for (int off = 32; off > 0; off >>= 1) s += __shfl_down(s, off, 64);
  if (j == 0) out[g] = s + b2[0];
}

extern "C" void kernel_launch(void* const* d_in, const int* in_sizes, int n_in,
                              void* d_out, int out_size, void* d_ws, size_t ws_size,
                              hipStream_t stream) {
  const int*   x     = (const int*)d_in[0];
  const int*   eidx  = (const int*)d_in[1];
  const int*   eattr = (const int*)d_in[2];
  const int*   batch = (const int*)d_in[3];
  const float* aemb  = (const float*)d_in[4];
  const float* bemb  = (const float*)d_in[5];
  const float* linw  = (const float*)d_in[6];
  const float* linb  = (const float*)d_in[7];
  const float* gamma = (const float*)d_in[8];
  const float* beta  = (const float*)d_in[9];
  const float* w1    = (const float*)d_in[10];
  const float* b1    = (const float*)d_in[11];
  const float* w2    = (const float*)d_in[12];
  const float* b2    = (const float*)d_in[13];
  float* out = (float*)d_out;

  int n  = in_sizes[3];        // 50000
  int ne = in_sizes[1] / 2;    // 600000

  char* p = (char*)d_ws;
  auto alloc = [&](size_t bytes) {
    char* r = p;
    p += (bytes + 255) & ~(size_t)255;
    return r;
  };
  float* bufA     = (float*)alloc((size_t)n * D * 4);   // h0 / z
  float* bufB     = (float*)alloc((size_t)n * D * 4);   // ht
  uint2* edges    = (uint2*)alloc((size_t)ne * 8);
  int*   rowoff   = (int*)alloc((size_t)(n + 1) * 4);
  int*   cursor   = (int*)alloc((size_t)n * 4);
  int*   deg      = (int*)alloc((size_t)n * 4);
  int*   gcnt     = (int*)alloc((size_t)NGRAPH * 4);
  int*   goff     = (int*)alloc((size_t)(NGRAPH + 1) * 4);
  float* tabT     = (float*)alloc((size_t)TAB_SZ * 4);
  float* partials = (float*)alloc((size_t)AGG_BLOCKS * 2 * D * 4);
  float* bnp      = (float*)alloc((size_t)4 * 2 * D * 4);
  float* poolb    = (float*)alloc((size_t)NGRAPH * D * 4);

  hipMemsetAsync(deg, 0, (size_t)n * 4, stream);
  hipMemsetAsync(gcnt, 0, (size_t)NGRAPH * 4, stream);

  embed_kernel<<<(n * 32 + 255) / 256, 256, 0, stream>>>(x, aemb, bufA, n);
  hist_kernel<<<(ne + 255) / 256, 256, 0, stream>>>(eidx + ne, deg, ne);
  scan_kernel<<<1, 1024, 0, stream>>>(deg, rowoff, cursor, n);
  scatter_kernel<<<(ne + 255) / 256, 256, 0, stream>>>(eidx, eidx + ne, eattr,
                                                       cursor, edges, ne);
  hist_kernel<<<(n + 255) / 256, 256, 0, stream>>>(batch, gcnt, n);
  scan_kernel<<<1, 1024, 0, stream>>>(gcnt, goff, (int*)nullptr, NGRAPH);

  for (int l = 0; l < 4; l++) {
    tabT_kernel<<<TAB_ROWS, D, 0, stream>>>(bemb + (size_t)l * 5 * 7 * D,
                                            linw + (size_t)l * D * D, tabT);
    gemm_kernel<<<(n + 63) / 64, 256, 0, stream>>>(
        bufA, linw + (size_t)l * D * D,
        l ? (bnp + (size_t)(l - 1) * 2 * D) : (const float*)nullptr, bufB, n);
    agg_kernel<<<AGG_BLOCKS, AGG_THREADS, 0, stream>>>(bufB, tabT, linb + (size_t)l * D,
                                                       edges, rowoff, bufA, partials, n);
    bn_finalize<<<1, D, 0, stream>>>(partials, gamma + (size_t)l * D,
                                     beta + (size_t)l * D, bnp + (size_t)l * 2 * D,
                                     AGG_BLOCKS, n);
  }
  pool_kernel<<<NGRAPH, D, 0, stream>>>(bufA, bnp + 3 * 2 * D, goff, gcnt, poolb);
  mlp_kernel<<<NGRAPH, 64, 0, stream>>>(poolb, w1, b1, w2, b2, out);
}

// Round 2
// 721.426 us; speedup vs baseline: 1.7435x; 1.7435x over previous
//
#include <hip/hip_runtime.h>
#include <hip/hip_bf16.h>
#include <stdint.h>

#define D 128
#define NGRAPH 256
#define BN_EPS 1e-5f
#define TAB_ROWS 105          // 49 (a0,a1) + 49 (a2,a3) + 7 (a4)
#define TAB_SZ (TAB_ROWS * D) // 13440 floats
#define AGG_BLOCKS 512
#define AGG_THREADS 1024

// ---------------- atom embedding: h0[n][c] = sum_f atom_emb[f][x[n,f]][c] ----
__global__ void embed_kernel(const int* __restrict__ x,
                             const float* __restrict__ atom_emb,
                             float* __restrict__ h0, int n) {
  int t = blockIdx.x * blockDim.x + threadIdx.x;
  int node = t >> 5;           // 32 threads/node, 4 channels each
  int cq = t & 31;
  if (node >= n) return;
  float4 acc = {0.f, 0.f, 0.f, 0.f};
#pragma unroll
  for (int f = 0; f < 9; f++) {
    int idx = x[node * 9 + f];
    const float4* row = (const float4*)(atom_emb + ((size_t)f * 120 + idx) * D);
    float4 v = row[cq];
    acc.x += v.x; acc.y += v.y; acc.z += v.z; acc.w += v.w;
  }
  ((float4*)(h0 + (size_t)node * D))[cq] = acc;
}

// ---------------- histogram (used for edge-dst degrees and graph counts) ----
__global__ void hist_kernel(const int* __restrict__ keys, int* __restrict__ cnt, int n) {
  int i = blockIdx.x * blockDim.x + threadIdx.x;
  if (i < n) atomicAdd(&cnt[keys[i]], 1);
}

// ------------- single-block exclusive scan, shfl-based (2 barriers/chunk) ---
__global__ __launch_bounds__(1024) void scan_kernel(const int* __restrict__ cnt,
                                                    int* __restrict__ off,
                                                    int* __restrict__ cursor, int n) {
  __shared__ int wsum[16];
  __shared__ int chunk_total;
  int tid = threadIdx.x;
  int lane = tid & 63, wid = tid >> 6;
  int base = 0;
  for (int start = 0; start < n; start += 1024) {
    int i = start + tid;
    int v = (i < n) ? cnt[i] : 0;
    int incl = v;
#pragma unroll
    for (int o = 1; o < 64; o <<= 1) {
      int t = __shfl_up(incl, o, 64);
      if (lane >= o) incl += t;
    }
    if (lane == 63) wsum[wid] = incl;
    __syncthreads();
    if (wid == 0) {
      int s = (lane < 16) ? wsum[lane] : 0;
#pragma unroll
      for (int o = 1; o < 16; o <<= 1) {
        int t = __shfl_up(s, o, 64);
        if (lane >= o) s += t;
      }
      if (lane < 16) wsum[lane] = s;   // inclusive prefix of wave sums
      if (lane == 15) chunk_total = s;
    }
    __syncthreads();
    int wprefix = (wid == 0) ? 0 : wsum[wid - 1];
    int excl = base + wprefix + incl - v;
    if (i < n) {
      off[i] = excl;
      if (cursor) cursor[i] = excl;
    }
    base += chunk_total;
    __syncthreads();   // protect wsum/chunk_total reuse next chunk
  }
  if (tid == 0) off[n] = base;
}

// ---------------- CSR scatter: sorted-by-dst edge records {src, packed-attr} -
__global__ void scatter_kernel(const int* __restrict__ src, const int* __restrict__ dst,
                               const int* __restrict__ attr, int* __restrict__ cursor,
                               uint2* __restrict__ edges, int ne) {
  int e = blockIdx.x * blockDim.x + threadIdx.x;
  if (e >= ne) return;
  int d = dst[e];
  int pos = atomicAdd(&cursor[d], 1);
  int a0 = attr[e * 5 + 0], a1 = attr[e * 5 + 1], a2 = attr[e * 5 + 2];
  int a3 = attr[e * 5 + 3], a4 = attr[e * 5 + 4];
  uint32_t packed = (uint32_t)(a0 * 7 + a1) | ((uint32_t)(a2 * 7 + a3) << 8) |
                    ((uint32_t)a4 << 16);
  uint2 r; r.x = (uint32_t)src[e]; r.y = packed;
  edges[pos] = r;
}

// ------- bond pair tables pre-multiplied by W^T:  tabT[r] = pairrow(r) @ W^T -
__global__ void tabT_kernel(const float* __restrict__ bond,  // [5][7][D] slice
                            const float* __restrict__ W,     // [D][D] (z=a@W^T)
                            float* __restrict__ tabT) {
  __shared__ float row[D];
  int r = blockIdx.x, c = threadIdx.x;
  float v;
  if (r < 49)
    v = bond[(0 * 7 + r / 7) * D + c] + bond[(1 * 7 + r % 7) * D + c];
  else if (r < 98) {
    int rr = r - 49;
    v = bond[(2 * 7 + rr / 7) * D + c] + bond[(3 * 7 + rr % 7) * D + c];
  } else
    v = bond[(4 * 7 + (r - 98)) * D + c];
  row[c] = v;
  __syncthreads();
  float s = 0.f;
  for (int k = 0; k < D; k++) s += row[k] * W[(size_t)c * D + k];
  tabT[(size_t)r * D + c] = s;
}

// ---------------- GEMM: out = act(in) @ W^T  --------------------------------
// act = BN(from raw stats gsum)+ReLU of prev layer, or identity if gsum==null
__global__ __launch_bounds__(256) void gemm_kernel(const float* __restrict__ in,
                                                   const float* __restrict__ W,
                                                   const float* __restrict__ gsum,
                                                   const float* __restrict__ gamma,
                                                   const float* __restrict__ beta,
                                                   float invN,
                                                   float* __restrict__ out, int M) {
  __shared__ float aT[32 * 68];   // [k][m], padded
  __shared__ float wT[32 * 132];  // [k][c], padded
  __shared__ float bns[2 * D];    // scale[D], shift[D]
  int tid = threadIdx.x;
  if (gsum && tid < D) {
    float s = gsum[tid], q = gsum[D + tid];
    float mu = s * invN;
    float var = q * invN - mu * mu;
    float sc = rsqrtf(var + BN_EPS) * gamma[tid];
    bns[tid] = sc;
    bns[D + tid] = beta[tid] - mu * sc;
  }
  int m0 = blockIdx.x * 64;
  int rg = tid >> 4, cg = tid & 15;
  float acc[4][8];
#pragma unroll
  for (int r = 0; r < 4; r++)
#pragma unroll
    for (int c = 0; c < 8; c++) acc[r][c] = 0.f;

  for (int kc = 0; kc < D; kc += 32) {
    __syncthreads();
    // stage A (64 rows x 32 k), transposed, with fused BN+ReLU
#pragma unroll
    for (int j = 0; j < 2; j++) {
      int idx = tid + 256 * j;
      int row = idx >> 3, kq = idx & 7;
      int grow = m0 + row;
      float4 v = {0.f, 0.f, 0.f, 0.f};
      if (grow < M) {
        v = *(const float4*)(in + (size_t)grow * D + kc + kq * 4);
        if (gsum) {
          float4 sc = *(const float4*)(bns + kc + kq * 4);
          float4 sh = *(const float4*)(bns + D + kc + kq * 4);
          v.x = fmaxf(v.x * sc.x + sh.x, 0.f);
          v.y = fmaxf(v.y * sc.y + sh.y, 0.f);
          v.z = fmaxf(v.z * sc.z + sh.z, 0.f);
          v.w = fmaxf(v.w * sc.w + sh.w, 0.f);
        }
      }
      aT[(kq * 4 + 0) * 68 + row] = v.x;
      aT[(kq * 4 + 1) * 68 + row] = v.y;
      aT[(kq * 4 + 2) * 68 + row] = v.z;
      aT[(kq * 4 + 3) * 68 + row] = v.w;
    }
    // stage W (128 c x 32 k), transposed
#pragma unroll
    for (int j = 0; j < 4; j++) {
      int idx = tid + 256 * j;
      int c = idx >> 3, kq = idx & 7;
      float4 v = *(const float4*)(W + (size_t)c * D + kc + kq * 4);
      wT[(kq * 4 + 0) * 132 + c] = v.x;
      wT[(kq * 4 + 1) * 132 + c] = v.y;
      wT[(kq * 4 + 2) * 132 + c] = v.z;
      wT[(kq * 4 + 3) * 132 + c] = v.w;
    }
    __syncthreads();
#pragma unroll
    for (int k = 0; k < 32; k++) {
      float4 a4 = *(const float4*)&aT[k * 68 + rg * 4];
      float4 w0 = *(const float4*)&wT[k * 132 + cg * 8];
      float4 w1 = *(const float4*)&wT[k * 132 + cg * 8 + 4];
      float a[4] = {a4.x, a4.y, a4.z, a4.w};
      float w[8] = {w0.x, w0.y, w0.z, w0.w, w1.x, w1.y, w1.z, w1.w};
#pragma unroll
      for (int r = 0; r < 4; r++)
#pragma unroll
        for (int c = 0; c < 8; c++) acc[r][c] += a[r] * w[c];
    }
  }
#pragma unroll
  for (int r = 0; r < 4; r++) {
    int row = m0 + rg * 4 + r;
    if (row < M) {
      float4 o0 = {acc[r][0], acc[r][1], acc[r][2], acc[r][3]};
      float4 o1 = {acc[r][4], acc[r][5], acc[r][6], acc[r][7]};
      *(float4*)(out + (size_t)row * D + cg * 8) = o0;
      *(float4*)(out + (size_t)row * D + cg * 8 + 4) = o1;
    }
  }
}

// --------- aggregation: z[i] = ht[i] + lin_b + zbT + sum_in (ht[src]+ebT) ----
// accumulates per-channel sum/sumsq into global gsum (for BN of this layer)
__global__ __launch_bounds__(AGG_THREADS) void agg_kernel(
    const float* __restrict__ ht, const float* __restrict__ tabT,
    const float* __restrict__ linb, const uint2* __restrict__ edges,
    const int* __restrict__ rowoff, float* __restrict__ z,
    float* __restrict__ gsum, int n) {
  __shared__ float tabs[TAB_SZ];
  __shared__ float psum[2 * D];
  int tid = threadIdx.x;
  for (int i = tid; i < TAB_SZ / 4; i += AGG_THREADS)
    ((float4*)tabs)[i] = ((const float4*)tabT)[i];
  if (tid < 2 * D) psum[tid] = 0.f;
  __syncthreads();

  int lane = tid & 63, half = lane >> 5, cq = lane & 31;
  int wid = (blockIdx.x * AGG_THREADS + tid) >> 6;
  int nw = (gridDim.x * AGG_THREADS) >> 6;
  float4 linb4 = ((const float4*)linb)[cq];
  float4 zb4;
  {
    float4 a = ((const float4*)(tabs + 0 * D))[cq];
    float4 b = ((const float4*)(tabs + 49 * D))[cq];
    float4 c = ((const float4*)(tabs + 98 * D))[cq];
    zb4.x = a.x + b.x + c.x; zb4.y = a.y + b.y + c.y;
    zb4.z = a.z + b.z + c.z; zb4.w = a.w + b.w + c.w;
  }
  float4 ssum = {0.f, 0.f, 0.f, 0.f}, ssq = {0.f, 0.f, 0.f, 0.f};

  for (int node = wid; node < n; node += nw) {
    float4 acc = {0.f, 0.f, 0.f, 0.f};
    if (half == 0) {  // self-loop + bias init on half 0
      float4 hv = ((const float4*)(ht + (size_t)node * D))[cq];
      acc.x = hv.x + linb4.x + zb4.x;
      acc.y = hv.y + linb4.y + zb4.y;
      acc.z = hv.z + linb4.z + zb4.z;
      acc.w = hv.w + linb4.w + zb4.w;
    }
    int s = rowoff[node], e = rowoff[node + 1];
    for (int j = s + half; j < e; j += 2) {
      uint2 rec = edges[j];
      float4 hv = ((const float4*)(ht + (size_t)rec.x * D))[cq];
      uint32_t p = rec.y;
      float4 b0 = *(const float4*)(tabs + (p & 255u) * D + cq * 4);
      float4 b1 = *(const float4*)(tabs + (49u + ((p >> 8) & 255u)) * D + cq * 4);
      float4 b2 = *(const float4*)(tabs + (98u + (p >> 16)) * D + cq * 4);
      acc.x += hv.x + b0.x + b1.x + b2.x;
      acc.y += hv.y + b0.y + b1.y + b2.y;
      acc.z += hv.z + b0.z + b1.z + b2.z;
      acc.w += hv.w + b0.w + b1.w + b2.w;
    }
    acc.x += __shfl_xor(acc.x, 32, 64);
    acc.y += __shfl_xor(acc.y, 32, 64);
    acc.z += __shfl_xor(acc.z, 32, 64);
    acc.w += __shfl_xor(acc.w, 32, 64);
    if (half == 0) {
      ((float4*)(z + (size_t)node * D))[cq] = acc;
      ssum.x += acc.x; ssum.y += acc.y; ssum.z += acc.z; ssum.w += acc.w;
      ssq.x += acc.x * acc.x; ssq.y += acc.y * acc.y;
      ssq.z += acc.z * acc.z; ssq.w += acc.w * acc.w;
    }
  }
  if (half == 0) {
    int c0 = cq * 4;
    atomicAdd(&psum[c0 + 0], ssum.x);
    atomicAdd(&psum[c0 + 1], ssum.y);
    atomicAdd(&psum[c0 + 2], ssum.z);
    atomicAdd(&psum[c0 + 3], ssum.w);
    atomicAdd(&psum[D + c0 + 0], ssq.x);
    atomicAdd(&psum[D + c0 + 1], ssq.y);
    atomicAdd(&psum[D + c0 + 2], ssq.z);
    atomicAdd(&psum[D + c0 + 3], ssq.w);
  }
  __syncthreads();
  if (tid < 2 * D) atomicAdd(&gsum[tid], psum[tid]);
}

// ---------------- mean pool over sorted batch segments (BN+ReLU fused) ------
__global__ void pool_kernel(const float* __restrict__ z, const float* __restrict__ gsum,
                            const float* __restrict__ gamma, const float* __restrict__ beta,
                            float invN,
                            const int* __restrict__ goff, const int* __restrict__ gcnt,
                            float* __restrict__ pool) {
  int g = blockIdx.x, c = threadIdx.x;  // 128 threads
  float s0 = gsum[c], q0 = gsum[D + c];
  float mu = s0 * invN;
  float var = q0 * invN - mu * mu;
  float sc = rsqrtf(var + BN_EPS) * gamma[c];
  float sh = beta[c] - mu * sc;
  int s = goff[g], cnt = gcnt[g];
  float acc = 0.f;
  for (int i = 0; i < cnt; i++) {
    float zv = z[(size_t)(s + i) * D + c];
    acc += fmaxf(zv * sc + sh, 0.f);
  }
  pool[(size_t)g * D + c] = acc / fmaxf((float)cnt, 1.f);
}

// ---------------- MLP head: out = relu(g@W1^T+b1)@W2^T + b2 -----------------
__global__ void mlp_kernel(const float* __restrict__ pool, const float* __restrict__ w1,
                           const float* __restrict__ b1, const float* __restrict__ w2,
                           const float* __restrict__ b2, float* __restrict__ out) {
  int g = blockIdx.x, j = threadIdx.x;  // 64 threads = 1 wave
  float s = b1[j];
  for (int k = 0; k < D; k++) s += pool[(size_t)g * D + k] * w1[(size_t)j * D + k];
  s = fmaxf(s, 0.f) * w2[j];
#pragma unroll
  for (int off = 32; off > 0; off >>= 1) s += __shfl_down(s, off, 64);
  if (j == 0) out[g] = s + b2[0];
}

extern "C" void kernel_launch(void* const* d_in, const int* in_sizes, int n_in,
                              void* d_out, int out_size, void* d_ws, size_t ws_size,
                              hipStream_t stream) {
  const int*   x     = (const int*)d_in[0];
  const int*   eidx  = (const int*)d_in[1];
  const int*   eattr = (const int*)d_in[2];
  const int*   batch = (const int*)d_in[3];
  const float* aemb  = (const float*)d_in[4];
  const float* bemb  = (const float*)d_in[5];
  const float* linw  = (const float*)d_in[6];
  const float* linb  = (const float*)d_in[7];
  const float* gamma = (const float*)d_in[8];
  const float* beta  = (const float*)d_in[9];
  const float* w1    = (const float*)d_in[10];
  const float* b1    = (const float*)d_in[11];
  const float* w2    = (const float*)d_in[12];
  const float* b2    = (const float*)d_in[13];
  float* out = (float*)d_out;

  int n  = in_sizes[3];        // 50000
  int ne = in_sizes[1] / 2;    // 600000
  float invN = 1.f / (float)n;

  char* p = (char*)d_ws;
  auto alloc = [&](size_t bytes) {
    char* r = p;
    p += (bytes + 255) & ~(size_t)255;
    return r;
  };
  float* bufA   = (float*)alloc((size_t)n * D * 4);   // h0 / z
  float* bufB   = (float*)alloc((size_t)n * D * 4);   // ht
  uint2* edges  = (uint2*)alloc((size_t)ne * 8);
  int*   rowoff = (int*)alloc((size_t)(n + 1) * 4);
  int*   cursor = (int*)alloc((size_t)n * 4);
  int*   deg    = (int*)alloc((size_t)n * 4);
  int*   gcnt   = (int*)alloc((size_t)NGRAPH * 4);
  int*   goff   = (int*)alloc((size_t)(NGRAPH + 1) * 4);
  float* tabT   = (float*)alloc((size_t)TAB_SZ * 4);
  float* gsum   = (float*)alloc((size_t)4 * 2 * D * 4);  // per-layer raw BN stats
  float* poolb  = (float*)alloc((size_t)NGRAPH * D * 4);

  hipMemsetAsync(deg, 0, (size_t)n * 4, stream);
  hipMemsetAsync(gcnt, 0, (size_t)NGRAPH * 4, stream);
  hipMemsetAsync(gsum, 0, (size_t)4 * 2 * D * 4, stream);

  embed_kernel<<<(n * 32 + 255) / 256, 256, 0, stream>>>(x, aemb, bufA, n);
  hist_kernel<<<(ne + 255) / 256, 256, 0, stream>>>(eidx + ne, deg, ne);
  scan_kernel<<<1, 1024, 0, stream>>>(deg, rowoff, cursor, n);
  scatter_kernel<<<(ne + 255) / 256, 256, 0, stream>>>(eidx, eidx + ne, eattr,
                                                       cursor, edges, ne);
  hist_kernel<<<(n + 255) / 256, 256, 0, stream>>>(batch, gcnt, n);
  scan_kernel<<<1, 1024, 0, stream>>>(gcnt, goff, (int*)nullptr, NGRAPH);

  for (int l = 0; l < 4; l++) {
    tabT_kernel<<<TAB_ROWS, D, 0, stream>>>(bemb + (size_t)l * 5 * 7 * D,
                                            linw + (size_t)l * D * D, tabT);
    gemm_kernel<<<(n + 63) / 64, 256, 0, stream>>>(
        bufA, linw + (size_t)l * D * D,
        l ? (gsum + (size_t)(l - 1) * 2 * D) : (const float*)nullptr,
        l ? (gamma + (size_t)(l - 1) * D) : (const float*)nullptr,
        l ? (beta + (size_t)(l - 1) * D) : (const float*)nullptr,
        invN, bufB, n);
    agg_kernel<<<AGG_BLOCKS, AGG_THREADS, 0, stream>>>(
        bufB, tabT, linb + (size_t)l * D, edges, rowoff, bufA,
        gsum + (size_t)l * 2 * D, n);
  }
  pool_kernel<<<NGRAPH, D, 0, stream>>>(bufA, gsum + 3 * 2 * D, gamma + 3 * D,
                                        beta + 3 * D, invN, goff, gcnt, poolb);
  mlp_kernel<<<NGRAPH, 64, 0, stream>>>(poolb, w1, b1, w2, b2, out);
}

// Round 3
// 594.054 us; speedup vs baseline: 2.1173x; 1.2144x over previous
//
#include <hip/hip_runtime.h>
#include <hip/hip_bf16.h>
#include <stdint.h>

#define D 128
#define NGRAPH 256
#define BN_EPS 1e-5f
#define TAB_ROWS 105          // 49 (a0,a1) + 49 (a2,a3) + 7 (a4)
#define TAB_SZ (TAB_ROWS * D) // 13440 floats
#define AGG_BLOCKS 512
#define AGG_THREADS 1024
#define MAXDEG 48             // Poisson(12) tail: P(>=48) ~ 6e-14 per node

// ---------------- atom embedding: h0[n][c] = sum_f atom_emb[f][x[n,f]][c] ----
__global__ void embed_kernel(const int* __restrict__ x,
                             const float* __restrict__ atom_emb,
                             float* __restrict__ h0, int n) {
  int t = blockIdx.x * blockDim.x + threadIdx.x;
  int node = t >> 5;           // 32 threads/node, 4 channels each
  int cq = t & 31;
  if (node >= n) return;
  float4 acc = {0.f, 0.f, 0.f, 0.f};
#pragma unroll
  for (int f = 0; f < 9; f++) {
    int idx = x[node * 9 + f];
    const float4* row = (const float4*)(atom_emb + ((size_t)f * 120 + idx) * D);
    float4 v = row[cq];
    acc.x += v.x; acc.y += v.y; acc.z += v.z; acc.w += v.w;
  }
  ((float4*)(h0 + (size_t)node * D))[cq] = acc;
}

// ------ fused CSR build: slot = atomicAdd(deg[dst]); edges[dst*MAXDEG+slot] --
__global__ void scatter_kernel(const int* __restrict__ src, const int* __restrict__ dst,
                               const int* __restrict__ attr, int* __restrict__ deg,
                               uint2* __restrict__ edges, int ne) {
  int e = blockIdx.x * blockDim.x + threadIdx.x;
  if (e >= ne) return;
  int d = dst[e];
  int slot = atomicAdd(&deg[d], 1);
  if (slot >= MAXDEG) return;  // statistically impossible; guard anyway
  int a0 = attr[e * 5 + 0], a1 = attr[e * 5 + 1], a2 = attr[e * 5 + 2];
  int a3 = attr[e * 5 + 3], a4 = attr[e * 5 + 4];
  uint32_t packed = (uint32_t)(a0 * 7 + a1) | ((uint32_t)(a2 * 7 + a3) << 8) |
                    ((uint32_t)a4 << 16);
  uint2 r; r.x = (uint32_t)src[e]; r.y = packed;
  edges[(size_t)d * MAXDEG + slot] = r;
}

// -------- graph offsets from sorted batch via boundary detection ------------
__global__ void goff_kernel(const int* __restrict__ batch, int n,
                            int* __restrict__ goff) {
  int i = blockIdx.x * blockDim.x + threadIdx.x;
  if (i >= n) return;
  int b = batch[i];
  if (i == 0) {
    for (int g = 0; g <= b; g++) goff[g] = 0;
  } else {
    int pb = batch[i - 1];
    for (int g = pb + 1; g <= b; g++) goff[g] = i;
  }
  if (i == n - 1) {
    for (int g = b + 1; g <= NGRAPH; g++) goff[g] = n;
  }
}

// ------- bond pair tables pre-multiplied by W^T:  tabT[r] = pairrow(r) @ W^T -
__global__ void tabT_kernel(const float* __restrict__ bond,  // [5][7][D] slice
                            const float* __restrict__ W,     // [D][D] (z=a@W^T)
                            float* __restrict__ tabT) {
  __shared__ float row[D];
  int r = blockIdx.x, c = threadIdx.x;
  float v;
  if (r < 49)
    v = bond[(0 * 7 + r / 7) * D + c] + bond[(1 * 7 + r % 7) * D + c];
  else if (r < 98) {
    int rr = r - 49;
    v = bond[(2 * 7 + rr / 7) * D + c] + bond[(3 * 7 + rr % 7) * D + c];
  } else
    v = bond[(4 * 7 + (r - 98)) * D + c];
  row[c] = v;
  __syncthreads();
  float s = 0.f;
  for (int k = 0; k < D; k++) s += row[k] * W[(size_t)c * D + k];
  tabT[(size_t)r * D + c] = s;
}

// ---------------- GEMM: out = act(in) @ W^T  --------------------------------
// act = BN(from raw stats gsum)+ReLU of prev layer, or identity if gsum==null
__global__ __launch_bounds__(256) void gemm_kernel(const float* __restrict__ in,
                                                   const float* __restrict__ W,
                                                   const float* __restrict__ gsum,
                                                   const float* __restrict__ gamma,
                                                   const float* __restrict__ beta,
                                                   float invN,
                                                   float* __restrict__ out, int M) {
  __shared__ float aT[32 * 68];   // [k][m], padded
  __shared__ float wT[32 * 132];  // [k][c], padded
  __shared__ float bns[2 * D];    // scale[D], shift[D]
  int tid = threadIdx.x;
  if (gsum && tid < D) {
    float s = gsum[tid], q = gsum[D + tid];
    float mu = s * invN;
    float var = q * invN - mu * mu;
    float sc = rsqrtf(var + BN_EPS) * gamma[tid];
    bns[tid] = sc;
    bns[D + tid] = beta[tid] - mu * sc;
  }
  int m0 = blockIdx.x * 64;
  int rg = tid >> 4, cg = tid & 15;
  float acc[4][8];
#pragma unroll
  for (int r = 0; r < 4; r++)
#pragma unroll
    for (int c = 0; c < 8; c++) acc[r][c] = 0.f;

  for (int kc = 0; kc < D; kc += 32) {
    __syncthreads();
    // stage A (64 rows x 32 k), transposed, with fused BN+ReLU
#pragma unroll
    for (int j = 0; j < 2; j++) {
      int idx = tid + 256 * j;
      int row = idx >> 3, kq = idx & 7;
      int grow = m0 + row;
      float4 v = {0.f, 0.f, 0.f, 0.f};
      if (grow < M) {
        v = *(const float4*)(in + (size_t)grow * D + kc + kq * 4);
        if (gsum) {
          float4 sc = *(const float4*)(bns + kc + kq * 4);
          float4 sh = *(const float4*)(bns + D + kc + kq * 4);
          v.x = fmaxf(v.x * sc.x + sh.x, 0.f);
          v.y = fmaxf(v.y * sc.y + sh.y, 0.f);
          v.z = fmaxf(v.z * sc.z + sh.z, 0.f);
          v.w = fmaxf(v.w * sc.w + sh.w, 0.f);
        }
      }
      aT[(kq * 4 + 0) * 68 + row] = v.x;
      aT[(kq * 4 + 1) * 68 + row] = v.y;
      aT[(kq * 4 + 2) * 68 + row] = v.z;
      aT[(kq * 4 + 3) * 68 + row] = v.w;
    }
    // stage W (128 c x 32 k), transposed
#pragma unroll
    for (int j = 0; j < 4; j++) {
      int idx = tid + 256 * j;
      int c = idx >> 3, kq = idx & 7;
      float4 v = *(const float4*)(W + (size_t)c * D + kc + kq * 4);
      wT[(kq * 4 + 0) * 132 + c] = v.x;
      wT[(kq * 4 + 1) * 132 + c] = v.y;
      wT[(kq * 4 + 2) * 132 + c] = v.z;
      wT[(kq * 4 + 3) * 132 + c] = v.w;
    }
    __syncthreads();
#pragma unroll
    for (int k = 0; k < 32; k++) {
      float4 a4 = *(const float4*)&aT[k * 68 + rg * 4];
      float4 w0 = *(const float4*)&wT[k * 132 + cg * 8];
      float4 w1 = *(const float4*)&wT[k * 132 + cg * 8 + 4];
      float a[4] = {a4.x, a4.y, a4.z, a4.w};
      float w[8] = {w0.x, w0.y, w0.z, w0.w, w1.x, w1.y, w1.z, w1.w};
#pragma unroll
      for (int r = 0; r < 4; r++)
#pragma unroll
        for (int c = 0; c < 8; c++) acc[r][c] += a[r] * w[c];
    }
  }
#pragma unroll
  for (int r = 0; r < 4; r++) {
    int row = m0 + rg * 4 + r;
    if (row < M) {
      float4 o0 = {acc[r][0], acc[r][1], acc[r][2], acc[r][3]};
      float4 o1 = {acc[r][4], acc[r][5], acc[r][6], acc[r][7]};
      *(float4*)(out + (size_t)row * D + cg * 8) = o0;
      *(float4*)(out + (size_t)row * D + cg * 8 + 4) = o1;
    }
  }
}

// --------- aggregation: z[i] = ht[i] + lin_b + zbT + sum_in (ht[src]+ebT) ----
// 4 groups of 16 lanes per wave -> 4 edges in flight; lane covers float4
// columns c16 and c16+16. Accumulates per-channel sum/sumsq into gsum.
__global__ __launch_bounds__(AGG_THREADS) void agg_kernel(
    const float* __restrict__ ht, const float* __restrict__ tabT,
    const float* __restrict__ linb, const uint2* __restrict__ edges,
    const int* __restrict__ deg, float* __restrict__ z,
    float* __restrict__ gsum, int n) {
  __shared__ float tabs[TAB_SZ];
  __shared__ float psum[2 * D];
  int tid = threadIdx.x;
  for (int i = tid; i < TAB_SZ / 4; i += AGG_THREADS)
    ((float4*)tabs)[i] = ((const float4*)tabT)[i];
  if (tid < 2 * D) psum[tid] = 0.f;
  __syncthreads();

  int lane = tid & 63;
  int g = lane >> 4;       // edge group 0..3
  int c16 = lane & 15;     // this lane covers float4 columns c16 and c16+16
  int wid = (blockIdx.x * AGG_THREADS + tid) >> 6;
  int nw = (gridDim.x * AGG_THREADS) >> 6;

  float4 lb_a = ((const float4*)linb)[c16];
  float4 lb_b = ((const float4*)linb)[c16 + 16];
  float4 zb_a, zb_b;
  {
    float4 a0 = ((const float4*)(tabs + 0 * D))[c16];
    float4 a1 = ((const float4*)(tabs + 49 * D))[c16];
    float4 a2 = ((const float4*)(tabs + 98 * D))[c16];
    zb_a.x = a0.x + a1.x + a2.x; zb_a.y = a0.y + a1.y + a2.y;
    zb_a.z = a0.z + a1.z + a2.z; zb_a.w = a0.w + a1.w + a2.w;
    float4 b0 = ((const float4*)(tabs + 0 * D))[c16 + 16];
    float4 b1 = ((const float4*)(tabs + 49 * D))[c16 + 16];
    float4 b2 = ((const float4*)(tabs + 98 * D))[c16 + 16];
    zb_b.x = b0.x + b1.x + b2.x; zb_b.y = b0.y + b1.y + b2.y;
    zb_b.z = b0.z + b1.z + b2.z; zb_b.w = b0.w + b1.w + b2.w;
  }
  float4 ssum_a = {0,0,0,0}, ssq_a = {0,0,0,0};
  float4 ssum_b = {0,0,0,0}, ssq_b = {0,0,0,0};

  for (int node = wid; node < n; node += nw) {
    float4 acc_a = {0,0,0,0}, acc_b = {0,0,0,0};
    if (g == 0) {  // self-loop + bias + zero-attr bond row, on group 0
      const float4* self = (const float4*)(ht + (size_t)node * D);
      float4 sa = self[c16], sb = self[c16 + 16];
      acc_a.x = sa.x + lb_a.x + zb_a.x; acc_a.y = sa.y + lb_a.y + zb_a.y;
      acc_a.z = sa.z + lb_a.z + zb_a.z; acc_a.w = sa.w + lb_a.w + zb_a.w;
      acc_b.x = sb.x + lb_b.x + zb_b.x; acc_b.y = sb.y + lb_b.y + zb_b.y;
      acc_b.z = sb.z + lb_b.z + zb_b.z; acc_b.w = sb.w + lb_b.w + zb_b.w;
    }
    int cnt = deg[node]; cnt = (cnt > MAXDEG) ? MAXDEG : cnt;
    int base = node * MAXDEG, e = base + cnt;
    for (int j = base + g; j < e; j += 4) {
      uint2 rec = edges[j];
      const float4* row = (const float4*)(ht + (size_t)rec.x * D);
      float4 hv_a = row[c16];
      float4 hv_b = row[c16 + 16];
      uint32_t p = rec.y;
      const float4* t0 = (const float4*)(tabs + (p & 255u) * D);
      const float4* t1 = (const float4*)(tabs + (49u + ((p >> 8) & 255u)) * D);
      const float4* t2 = (const float4*)(tabs + (98u + (p >> 16)) * D);
      float4 b0a = t0[c16], b1a = t1[c16], b2a = t2[c16];
      float4 b0b = t0[c16 + 16], b1b = t1[c16 + 16], b2b = t2[c16 + 16];
      acc_a.x += hv_a.x + b0a.x + b1a.x + b2a.x;
      acc_a.y += hv_a.y + b0a.y + b1a.y + b2a.y;
      acc_a.z += hv_a.z + b0a.z + b1a.z + b2a.z;
      acc_a.w += hv_a.w + b0a.w + b1a.w + b2a.w;
      acc_b.x += hv_b.x + b0b.x + b1b.x + b2b.x;
      acc_b.y += hv_b.y + b0b.y + b1b.y + b2b.y;
      acc_b.z += hv_b.z + b0b.z + b1b.z + b2b.z;
      acc_b.w += hv_b.w + b0b.w + b1b.w + b2b.w;
    }
#pragma unroll
    for (int off = 16; off <= 32; off <<= 1) {
      acc_a.x += __shfl_xor(acc_a.x, off, 64);
      acc_a.y += __shfl_xor(acc_a.y, off, 64);
      acc_a.z += __shfl_xor(acc_a.z, off, 64);
      acc_a.w += __shfl_xor(acc_a.w, off, 64);
      acc_b.x += __shfl_xor(acc_b.x, off, 64);
      acc_b.y += __shfl_xor(acc_b.y, off, 64);
      acc_b.z += __shfl_xor(acc_b.z, off, 64);
      acc_b.w += __shfl_xor(acc_b.w, off, 64);
    }
    if (g == 0) {
      float4* zr = (float4*)(z + (size_t)node * D);
      zr[c16] = acc_a;
      zr[c16 + 16] = acc_b;
      ssum_a.x += acc_a.x; ssum_a.y += acc_a.y; ssum_a.z += acc_a.z; ssum_a.w += acc_a.w;
      ssq_a.x += acc_a.x * acc_a.x; ssq_a.y += acc_a.y * acc_a.y;
      ssq_a.z += acc_a.z * acc_a.z; ssq_a.w += acc_a.w * acc_a.w;
      ssum_b.x += acc_b.x; ssum_b.y += acc_b.y; ssum_b.z += acc_b.z; ssum_b.w += acc_b.w;
      ssq_b.x += acc_b.x * acc_b.x; ssq_b.y += acc_b.y * acc_b.y;
      ssq_b.z += acc_b.z * acc_b.z; ssq_b.w += acc_b.w * acc_b.w;
    }
  }
  if (g == 0) {
    int ca = c16 * 4, cb = (c16 + 16) * 4;
    atomicAdd(&psum[ca + 0], ssum_a.x); atomicAdd(&psum[ca + 1], ssum_a.y);
    atomicAdd(&psum[ca + 2], ssum_a.z); atomicAdd(&psum[ca + 3], ssum_a.w);
    atomicAdd(&psum[cb + 0], ssum_b.x); atomicAdd(&psum[cb + 1], ssum_b.y);
    atomicAdd(&psum[cb + 2], ssum_b.z); atomicAdd(&psum[cb + 3], ssum_b.w);
    atomicAdd(&psum[D + ca + 0], ssq_a.x); atomicAdd(&psum[D + ca + 1], ssq_a.y);
    atomicAdd(&psum[D + ca + 2], ssq_a.z); atomicAdd(&psum[D + ca + 3], ssq_a.w);
    atomicAdd(&psum[D + cb + 0], ssq_b.x); atomicAdd(&psum[D + cb + 1], ssq_b.y);
    atomicAdd(&psum[D + cb + 2], ssq_b.z); atomicAdd(&psum[D + cb + 3], ssq_b.w);
  }
  __syncthreads();
  if (tid < 2 * D) atomicAdd(&gsum[tid], psum[tid]);
}

// ---------------- mean pool over sorted batch segments (BN+ReLU fused) ------
__global__ void pool_kernel(const float* __restrict__ z, const float* __restrict__ gsum,
                            const float* __restrict__ gamma, const float* __restrict__ beta,
                            float invN, const int* __restrict__ goff,
                            float* __restrict__ pool) {
  int g = blockIdx.x, c = threadIdx.x;  // 128 threads
  float s0 = gsum[c], q0 = gsum[D + c];
  float mu = s0 * invN;
  float var = q0 * invN - mu * mu;
  float sc = rsqrtf(var + BN_EPS) * gamma[c];
  float sh = beta[c] - mu * sc;
  int s = goff[g], cnt = goff[g + 1] - s;
  float acc = 0.f;
  for (int i = 0; i < cnt; i++) {
    float zv = z[(size_t)(s + i) * D + c];
    acc += fmaxf(zv * sc + sh, 0.f);
  }
  pool[(size_t)g * D + c] = acc / fmaxf((float)cnt, 1.f);
}

// ---------------- MLP head: out = relu(g@W1^T+b1)@W2^T + b2 -----------------
__global__ void mlp_kernel(const float* __restrict__ pool, const float* __restrict__ w1,
                           const float* __restrict__ b1, const float* __restrict__ w2,
                           const float* __restrict__ b2, float* __restrict__ out) {
  int g = blockIdx.x, j = threadIdx.x;  // 64 threads = 1 wave
  float s = b1[j];
  for (int k = 0; k < D; k++) s += pool[(size_t)g * D + k] * w1[(size_t)j * D + k];
  s = fmaxf(s, 0.f) * w2[j];
#pragma unroll
  for (int off = 32; off > 0; off >>= 1) s += __shfl_down(s, off, 64);
  if (j == 0) out[g] = s + b2[0];
}

extern "C" void kernel_launch(void* const* d_in, const int* in_sizes, int n_in,
                              void* d_out, int out_size, void* d_ws, size_t ws_size,
                              hipStream_t stream) {
  const int*   x     = (const int*)d_in[0];
  const int*   eidx  = (const int*)d_in[1];
  const int*   eattr = (const int*)d_in[2];
  const int*   batch = (const int*)d_in[3];
  const float* aemb  = (const float*)d_in[4];
  const float* bemb  = (const float*)d_in[5];
  const float* linw  = (const float*)d_in[6];
  const float* linb  = (const float*)d_in[7];
  const float* gamma = (const float*)d_in[8];
  const float* beta  = (const float*)d_in[9];
  const float* w1    = (const float*)d_in[10];
  const float* b1    = (const float*)d_in[11];
  const float* w2    = (const float*)d_in[12];
  const float* b2    = (const float*)d_in[13];
  float* out = (float*)d_out;

  int n  = in_sizes[3];        // 50000
  int ne = in_sizes[1] / 2;    // 600000
  float invN = 1.f / (float)n;

  char* p = (char*)d_ws;
  auto alloc = [&](size_t bytes) {
    char* r = p;
    p += (bytes + 255) & ~(size_t)255;
    return r;
  };
  float* bufA   = (float*)alloc((size_t)n * D * 4);        // h0 / z
  float* bufB   = (float*)alloc((size_t)n * D * 4);        // ht
  uint2* edges  = (uint2*)alloc((size_t)n * MAXDEG * 8);   // strided CSR
  int*   deg    = (int*)alloc((size_t)n * 4);
  int*   goff   = (int*)alloc((size_t)(NGRAPH + 1) * 4);
  float* tabT   = (float*)alloc((size_t)TAB_SZ * 4);
  float* gsum   = (float*)alloc((size_t)4 * 2 * D * 4);    // per-layer raw BN stats
  float* poolb  = (float*)alloc((size_t)NGRAPH * D * 4);

  hipMemsetAsync(deg, 0, (size_t)n * 4, stream);
  hipMemsetAsync(gsum, 0, (size_t)4 * 2 * D * 4, stream);

  embed_kernel<<<(n * 32 + 255) / 256, 256, 0, stream>>>(x, aemb, bufA, n);
  scatter_kernel<<<(ne + 255) / 256, 256, 0, stream>>>(eidx, eidx + ne, eattr,
                                                       deg, edges, ne);
  goff_kernel<<<(n + 255) / 256, 256, 0, stream>>>(batch, n, goff);

  for (int l = 0; l < 4; l++) {
    tabT_kernel<<<TAB_ROWS, D, 0, stream>>>(bemb + (size_t)l * 5 * 7 * D,
                                            linw + (size_t)l * D * D, tabT);
    gemm_kernel<<<(n + 63) / 64, 256, 0, stream>>>(
        bufA, linw + (size_t)l * D * D,
        l ? (gsum + (size_t)(l - 1) * 2 * D) : (const float*)nullptr,
        l ? (gamma + (size_t)(l - 1) * D) : (const float*)nullptr,
        l ? (beta + (size_t)(l - 1) * D) : (const float*)nullptr,
        invN, bufB, n);
    agg_kernel<<<AGG_BLOCKS, AGG_THREADS, 0, stream>>>(
        bufB, tabT, linb + (size_t)l * D, edges, deg, bufA,
        gsum + (size_t)l * 2 * D, n);
  }
  pool_kernel<<<NGRAPH, D, 0, stream>>>(bufA, gsum + 3 * 2 * D, gamma + 3 * D,
                                        beta + 3 * D, invN, goff, poolb);
  mlp_kernel<<<NGRAPH, 64, 0, stream>>>(poolb, w1, b1, w2, b2, out);
}

// Round 4
// 579.313 us; speedup vs baseline: 2.1712x; 1.0254x over previous
//
#include <hip/hip_runtime.h>
#include <hip/hip_bf16.h>
#include <stdint.h>

#define D 128
#define NGRAPH 256
#define BN_EPS 1e-5f
#define TAB_ROWS 105          // 49 (a0,a1) + 49 (a2,a3) + 7 (a4)
#define TAB_SZ (TAB_ROWS * D) // 13440 bf16 elements
#define AGG_BLOCKS 512
#define AGG_THREADS 1024
#define MAXDEG 48             // Poisson(12) tail: P(>=48) ~ 6e-14 per node

typedef unsigned short u16;

// ---- bf16 pack/unpack helpers (storage bf16, all math fp32) ----------------
__device__ inline u16 f2bf(float a) {
  return __builtin_bit_cast(u16, __float2bfloat16(a));
}
__device__ inline uint32_t pk2(float a, float b) {
  return (uint32_t)f2bf(a) | ((uint32_t)f2bf(b) << 16);
}
__device__ inline float bflo(uint32_t u) { return __builtin_bit_cast(float, u << 16); }
__device__ inline float bfhi(uint32_t u) { return __builtin_bit_cast(float, u & 0xffff0000u); }
__device__ inline void unpack8(uint4 v, float* f) {
  f[0] = bflo(v.x); f[1] = bfhi(v.x); f[2] = bflo(v.y); f[3] = bfhi(v.y);
  f[4] = bflo(v.z); f[5] = bfhi(v.z); f[6] = bflo(v.w); f[7] = bfhi(v.w);
}

// ---------------- atom embedding: h0[n][c] = sum_f atom_emb[f][x[n,f]][c] ----
__global__ void embed_kernel(const int* __restrict__ x,
                             const float* __restrict__ atom_emb,
                             float* __restrict__ h0, int n) {
  int t = blockIdx.x * blockDim.x + threadIdx.x;
  int node = t >> 5;           // 32 threads/node, 4 channels each
  int cq = t & 31;
  if (node >= n) return;
  float4 acc = {0.f, 0.f, 0.f, 0.f};
#pragma unroll
  for (int f = 0; f < 9; f++) {
    int idx = x[node * 9 + f];
    const float4* row = (const float4*)(atom_emb + ((size_t)f * 120 + idx) * D);
    float4 v = row[cq];
    acc.x += v.x; acc.y += v.y; acc.z += v.z; acc.w += v.w;
  }
  ((float4*)(h0 + (size_t)node * D))[cq] = acc;
}

// ------ fused CSR build: slot = atomicAdd(deg[dst]); edges[dst*MAXDEG+slot] --
__global__ void scatter_kernel(const int* __restrict__ src, const int* __restrict__ dst,
                               const int* __restrict__ attr, int* __restrict__ deg,
                               uint2* __restrict__ edges, int ne) {
  int e = blockIdx.x * blockDim.x + threadIdx.x;
  if (e >= ne) return;
  int d = dst[e];
  int slot = atomicAdd(&deg[d], 1);
  if (slot >= MAXDEG) return;  // statistically impossible; guard anyway
  int a0 = attr[e * 5 + 0], a1 = attr[e * 5 + 1], a2 = attr[e * 5 + 2];
  int a3 = attr[e * 5 + 3], a4 = attr[e * 5 + 4];
  uint32_t packed = (uint32_t)(a0 * 7 + a1) | ((uint32_t)(a2 * 7 + a3) << 8) |
                    ((uint32_t)a4 << 16);
  uint2 r; r.x = (uint32_t)src[e]; r.y = packed;
  edges[(size_t)d * MAXDEG + slot] = r;
}

// -------- graph offsets from sorted batch via boundary detection ------------
__global__ void goff_kernel(const int* __restrict__ batch, int n,
                            int* __restrict__ goff) {
  int i = blockIdx.x * blockDim.x + threadIdx.x;
  if (i >= n) return;
  int b = batch[i];
  if (i == 0) {
    for (int g = 0; g <= b; g++) goff[g] = 0;
  } else {
    int pb = batch[i - 1];
    for (int g = pb + 1; g <= b; g++) goff[g] = i;
  }
  if (i == n - 1) {
    for (int g = b + 1; g <= NGRAPH; g++) goff[g] = n;
  }
}

// ------- bond pair tables pre-multiplied by W^T, stored bf16 ----------------
__global__ void tabT_kernel(const float* __restrict__ bond,  // [5][7][D] slice
                            const float* __restrict__ W,     // [D][D] (z=a@W^T)
                            u16* __restrict__ tabT) {
  __shared__ float row[D];
  int r = blockIdx.x, c = threadIdx.x;
  float v;
  if (r < 49)
    v = bond[(0 * 7 + r / 7) * D + c] + bond[(1 * 7 + r % 7) * D + c];
  else if (r < 98) {
    int rr = r - 49;
    v = bond[(2 * 7 + rr / 7) * D + c] + bond[(3 * 7 + rr % 7) * D + c];
  } else
    v = bond[(4 * 7 + (r - 98)) * D + c];
  row[c] = v;
  __syncthreads();
  float s = 0.f;
  for (int k = 0; k < D; k++) s += row[k] * W[(size_t)c * D + k];
  tabT[(size_t)r * D + c] = f2bf(s);
}

// ---------------- GEMM: out(bf16) = act(in) @ W^T ---------------------------
// act = BN(from raw stats gsum)+ReLU of prev layer, or identity if gsum==null
__global__ __launch_bounds__(256) void gemm_kernel(const float* __restrict__ in,
                                                   const float* __restrict__ W,
                                                   const float* __restrict__ gsum,
                                                   const float* __restrict__ gamma,
                                                   const float* __restrict__ beta,
                                                   float invN,
                                                   u16* __restrict__ out, int M) {
  __shared__ float aT[32 * 68];   // [k][m], padded
  __shared__ float wT[32 * 132];  // [k][c], padded
  __shared__ float bns[2 * D];    // scale[D], shift[D]
  int tid = threadIdx.x;
  if (gsum && tid < D) {
    float s = gsum[tid], q = gsum[D + tid];
    float mu = s * invN;
    float var = q * invN - mu * mu;
    float sc = rsqrtf(var + BN_EPS) * gamma[tid];
    bns[tid] = sc;
    bns[D + tid] = beta[tid] - mu * sc;
  }
  int m0 = blockIdx.x * 64;
  int rg = tid >> 4, cg = tid & 15;
  float acc[4][8];
#pragma unroll
  for (int r = 0; r < 4; r++)
#pragma unroll
    for (int c = 0; c < 8; c++) acc[r][c] = 0.f;

  for (int kc = 0; kc < D; kc += 32) {
    __syncthreads();
    // stage A (64 rows x 32 k), transposed, with fused BN+ReLU
#pragma unroll
    for (int j = 0; j < 2; j++) {
      int idx = tid + 256 * j;
      int row = idx >> 3, kq = idx & 7;
      int grow = m0 + row;
      float4 v = {0.f, 0.f, 0.f, 0.f};
      if (grow < M) {
        v = *(const float4*)(in + (size_t)grow * D + kc + kq * 4);
        if (gsum) {
          float4 sc = *(const float4*)(bns + kc + kq * 4);
          float4 sh = *(const float4*)(bns + D + kc + kq * 4);
          v.x = fmaxf(v.x * sc.x + sh.x, 0.f);
          v.y = fmaxf(v.y * sc.y + sh.y, 0.f);
          v.z = fmaxf(v.z * sc.z + sh.z, 0.f);
          v.w = fmaxf(v.w * sc.w + sh.w, 0.f);
        }
      }
      aT[(kq * 4 + 0) * 68 + row] = v.x;
      aT[(kq * 4 + 1) * 68 + row] = v.y;
      aT[(kq * 4 + 2) * 68 + row] = v.z;
      aT[(kq * 4 + 3) * 68 + row] = v.w;
    }
    // stage W (128 c x 32 k), transposed
#pragma unroll
    for (int j = 0; j < 4; j++) {
      int idx = tid + 256 * j;
      int c = idx >> 3, kq = idx & 7;
      float4 v = *(const float4*)(W + (size_t)c * D + kc + kq * 4);
      wT[(kq * 4 + 0) * 132 + c] = v.x;
      wT[(kq * 4 + 1) * 132 + c] = v.y;
      wT[(kq * 4 + 2) * 132 + c] = v.z;
      wT[(kq * 4 + 3) * 132 + c] = v.w;
    }
    __syncthreads();
#pragma unroll
    for (int k = 0; k < 32; k++) {
      float4 a4 = *(const float4*)&aT[k * 68 + rg * 4];
      float4 w0 = *(const float4*)&wT[k * 132 + cg * 8];
      float4 w1 = *(const float4*)&wT[k * 132 + cg * 8 + 4];
      float a[4] = {a4.x, a4.y, a4.z, a4.w};
      float w[8] = {w0.x, w0.y, w0.z, w0.w, w1.x, w1.y, w1.z, w1.w};
#pragma unroll
      for (int r = 0; r < 4; r++)
#pragma unroll
        for (int c = 0; c < 8; c++) acc[r][c] += a[r] * w[c];
    }
  }
#pragma unroll
  for (int r = 0; r < 4; r++) {
    int row = m0 + rg * 4 + r;
    if (row < M) {
      uint4 o;
      o.x = pk2(acc[r][0], acc[r][1]);
      o.y = pk2(acc[r][2], acc[r][3]);
      o.z = pk2(acc[r][4], acc[r][5]);
      o.w = pk2(acc[r][6], acc[r][7]);
      *(uint4*)(out + (size_t)row * D + cg * 8) = o;
    }
  }
}

// --------- aggregation: z[i] = ht[i] + lin_b + zbT + sum_in (ht[src]+ebT) ----
// ht and bond tables are bf16 (256 B rows); accumulate fp32. 4 groups of 16
// lanes per wave; lane covers 8 channels (c8*8..c8*8+7).
__global__ __launch_bounds__(AGG_THREADS) void agg_kernel(
    const u16* __restrict__ ht, const u16* __restrict__ tabT,
    const float* __restrict__ linb, const uint2* __restrict__ edges,
    const int* __restrict__ deg, float* __restrict__ z,
    float* __restrict__ gsum, int n) {
  __shared__ u16 tabs[TAB_SZ];        // 26.9 KB
  __shared__ float psum[2 * D];
  int tid = threadIdx.x;
  for (int i = tid; i < TAB_SZ / 8; i += AGG_THREADS)
    ((uint4*)tabs)[i] = ((const uint4*)tabT)[i];
  if (tid < 2 * D) psum[tid] = 0.f;
  __syncthreads();

  int lane = tid & 63;
  int g = lane >> 4;       // edge group 0..3
  int c8 = lane & 15;      // covers channels c8*8 .. c8*8+7
  int wid = (blockIdx.x * AGG_THREADS + tid) >> 6;
  int nw = (gridDim.x * AGG_THREADS) >> 6;

  float lb[8], zb[8];
  {
    float4 l0 = ((const float4*)linb)[c8 * 2];
    float4 l1 = ((const float4*)linb)[c8 * 2 + 1];
    lb[0] = l0.x; lb[1] = l0.y; lb[2] = l0.z; lb[3] = l0.w;
    lb[4] = l1.x; lb[5] = l1.y; lb[6] = l1.z; lb[7] = l1.w;
    float t0[8], t1[8], t2[8];
    unpack8(*(const uint4*)(tabs + 0 * D + c8 * 8), t0);
    unpack8(*(const uint4*)(tabs + 49 * D + c8 * 8), t1);
    unpack8(*(const uint4*)(tabs + 98 * D + c8 * 8), t2);
#pragma unroll
    for (int i = 0; i < 8; i++) zb[i] = t0[i] + t1[i] + t2[i];
  }
  float ssum[8], ssq[8];
#pragma unroll
  for (int i = 0; i < 8; i++) { ssum[i] = 0.f; ssq[i] = 0.f; }

  for (int node = wid; node < n; node += nw) {
    float acc[8];
    if (g == 0) {  // self-loop + bias + zero-attr bond row, on group 0
      float sv[8];
      unpack8(*(const uint4*)(ht + (size_t)node * D + c8 * 8), sv);
#pragma unroll
      for (int i = 0; i < 8; i++) acc[i] = sv[i] + lb[i] + zb[i];
    } else {
#pragma unroll
      for (int i = 0; i < 8; i++) acc[i] = 0.f;
    }
    int cnt = deg[node]; cnt = (cnt > MAXDEG) ? MAXDEG : cnt;
    int base = node * MAXDEG, e = base + cnt;
    for (int j = base + g; j < e; j += 4) {
      uint2 rec = edges[j];
      uint4 hvv = *(const uint4*)(ht + (size_t)rec.x * D + c8 * 8);
      uint32_t p = rec.y;
      uint4 t0v = *(const uint4*)(tabs + (p & 255u) * D + c8 * 8);
      uint4 t1v = *(const uint4*)(tabs + (49u + ((p >> 8) & 255u)) * D + c8 * 8);
      uint4 t2v = *(const uint4*)(tabs + (98u + (p >> 16)) * D + c8 * 8);
      float hv[8], b0[8], b1[8], b2[8];
      unpack8(hvv, hv); unpack8(t0v, b0); unpack8(t1v, b1); unpack8(t2v, b2);
#pragma unroll
      for (int i = 0; i < 8; i++) acc[i] += hv[i] + b0[i] + b1[i] + b2[i];
    }
#pragma unroll
    for (int off = 16; off <= 32; off <<= 1)
#pragma unroll
      for (int i = 0; i < 8; i++) acc[i] += __shfl_xor(acc[i], off, 64);
    if (g == 0) {
      float4 za = {acc[0], acc[1], acc[2], acc[3]};
      float4 zb4 = {acc[4], acc[5], acc[6], acc[7]};
      float4* zr = (float4*)(z + (size_t)node * D);
      zr[c8 * 2] = za;
      zr[c8 * 2 + 1] = zb4;
#pragma unroll
      for (int i = 0; i < 8; i++) {
        ssum[i] += acc[i];
        ssq[i] += acc[i] * acc[i];
      }
    }
  }
  if (g == 0) {
    int c0 = c8 * 8;
#pragma unroll
    for (int i = 0; i < 8; i++) {
      atomicAdd(&psum[c0 + i], ssum[i]);
      atomicAdd(&psum[D + c0 + i], ssq[i]);
    }
  }
  __syncthreads();
  if (tid < 2 * D) atomicAdd(&gsum[tid], psum[tid]);
}

// ---------------- mean pool over sorted batch segments (BN+ReLU fused) ------
__global__ void pool_kernel(const float* __restrict__ z, const float* __restrict__ gsum,
                            const float* __restrict__ gamma, const float* __restrict__ beta,
                            float invN, const int* __restrict__ goff,
                            float* __restrict__ pool) {
  int g = blockIdx.x, c = threadIdx.x;  // 128 threads
  float s0 = gsum[c], q0 = gsum[D + c];
  float mu = s0 * invN;
  float var = q0 * invN - mu * mu;
  float sc = rsqrtf(var + BN_EPS) * gamma[c];
  float sh = beta[c] - mu * sc;
  int s = goff[g], cnt = goff[g + 1] - s;
  float acc = 0.f;
  for (int i = 0; i < cnt; i++) {
    float zv = z[(size_t)(s + i) * D + c];
    acc += fmaxf(zv * sc + sh, 0.f);
  }
  pool[(size_t)g * D + c] = acc / fmaxf((float)cnt, 1.f);
}

// ---------------- MLP head: out = relu(g@W1^T+b1)@W2^T + b2 -----------------
__global__ void mlp_kernel(const float* __restrict__ pool, const float* __restrict__ w1,
                           const float* __restrict__ b1, const float* __restrict__ w2,
                           const float* __restrict__ b2, float* __restrict__ out) {
  int g = blockIdx.x, j = threadIdx.x;  // 64 threads = 1 wave
  float s = b1[j];
  for (int k = 0; k < D; k++) s += pool[(size_t)g * D + k] * w1[(size_t)j * D + k];
  s = fmaxf(s, 0.f) * w2[j];
#pragma unroll
  for (int off = 32; off > 0; off >>= 1) s += __shfl_down(s, off, 64);
  if (j == 0) out[g] = s + b2[0];
}

extern "C" void kernel_launch(void* const* d_in, const int* in_sizes, int n_in,
                              void* d_out, int out_size, void* d_ws, size_t ws_size,
                              hipStream_t stream) {
  const int*   x     = (const int*)d_in[0];
  const int*   eidx  = (const int*)d_in[1];
  const int*   eattr = (const int*)d_in[2];
  const int*   batch = (const int*)d_in[3];
  const float* aemb  = (const float*)d_in[4];
  const float* bemb  = (const float*)d_in[5];
  const float* linw  = (const float*)d_in[6];
  const float* linb  = (const float*)d_in[7];
  const float* gamma = (const float*)d_in[8];
  const float* beta  = (const float*)d_in[9];
  const float* w1    = (const float*)d_in[10];
  const float* b1    = (const float*)d_in[11];
  const float* w2    = (const float*)d_in[12];
  const float* b2    = (const float*)d_in[13];
  float* out = (float*)d_out;

  int n  = in_sizes[3];        // 50000
  int ne = in_sizes[1] / 2;    // 600000
  float invN = 1.f / (float)n;

  char* p = (char*)d_ws;
  auto alloc = [&](size_t bytes) {
    char* r = p;
    p += (bytes + 255) & ~(size_t)255;
    return r;
  };
  float* bufA   = (float*)alloc((size_t)n * D * 4);        // h0 / z (fp32)
  u16*   bufB   = (u16*)alloc((size_t)n * D * 2);          // ht (bf16)
  uint2* edges  = (uint2*)alloc((size_t)n * MAXDEG * 8);   // strided CSR
  int*   deg    = (int*)alloc((size_t)n * 4);
  int*   goff   = (int*)alloc((size_t)(NGRAPH + 1) * 4);
  u16*   tabT   = (u16*)alloc((size_t)TAB_SZ * 2);
  float* gsum   = (float*)alloc((size_t)4 * 2 * D * 4);    // per-layer raw BN stats
  float* poolb  = (float*)alloc((size_t)NGRAPH * D * 4);

  hipMemsetAsync(deg, 0, (size_t)n * 4, stream);
  hipMemsetAsync(gsum, 0, (size_t)4 * 2 * D * 4, stream);

  embed_kernel<<<(n * 32 + 255) / 256, 256, 0, stream>>>(x, aemb, bufA, n);
  scatter_kernel<<<(ne + 255) / 256, 256, 0, stream>>>(eidx, eidx + ne, eattr,
                                                       deg, edges, ne);
  goff_kernel<<<(n + 255) / 256, 256, 0, stream>>>(batch, n, goff);

  for (int l = 0; l < 4; l++) {
    tabT_kernel<<<TAB_ROWS, D, 0, stream>>>(bemb + (size_t)l * 5 * 7 * D,
                                            linw + (size_t)l * D * D, tabT);
    gemm_kernel<<<(n + 63) / 64, 256, 0, stream>>>(
        bufA, linw + (size_t)l * D * D,
        l ? (gsum + (size_t)(l - 1) * 2 * D) : (const float*)nullptr,
        l ? (gamma + (size_t)(l - 1) * D) : (const float*)nullptr,
        l ? (beta + (size_t)(l - 1) * D) : (const float*)nullptr,
        invN, bufB, n);
    agg_kernel<<<AGG_BLOCKS, AGG_THREADS, 0, stream>>>(
        bufB, tabT, linb + (size_t)l * D, edges, deg, bufA,
        gsum + (size_t)l * 2 * D, n);
  }
  pool_kernel<<<NGRAPH, D, 0, stream>>>(bufA, gsum + 3 * 2 * D, gamma + 3 * D,
                                        beta + 3 * D, invN, goff, poolb);
  mlp_kernel<<<NGRAPH, 64, 0, stream>>>(poolb, w1, b1, w2, b2, out);
}